// Round 2
// baseline (260.153 us; speedup 1.0000x reference)
//
#include <hip/hip_runtime.h>

// SparseMaxPool: out[b,d,r,c] = max(x[b,d,r..c]) on a sparse (r,c) pattern, else 0.
// R2: slice-invariant descriptor tables in d_ws (built per call by sp_init):
//   - bdesc[2560] u32: build per-offset window-max value array from doubling table
//   - odesc[16384] u16: per-element LDS word address (invalid -> zero slot)
// Main kernel per element: 1 cached u16 load + 1 ds_read_b32 + coalesced float4 store.

#define NN 128
#define SLICE_ELEMS (NN * NN)
#define VOFF 784            // value array base in LDS words (doubling table uses 0..776)
#define NVAL 2560           // padded value-array slots (2548 real)
#define ZERO_SLOT (VOFF + NVAL)
#define LDS_WORDS (VOFF + NVAL + 1)   // 3345 floats = 13380 B
#define NBUILD 2560
#define NODESC 16384

__device__ __forceinline__ void seg_params(int s, int& o, int& sh) {
    if (s < 16)      { o = s;                sh = 0; }
    else if (s < 24) { o = 17 + 2 * (s - 16); sh = 1; }
    else if (s < 32) { o = 35 + 4 * (s - 24); sh = 2; }
    else             { o = 71 + 8 * (s - 32); sh = 3; }
}

__global__ __launch_bounds__(256) void sp_init(unsigned int* __restrict__ bdesc,
                                               unsigned short* __restrict__ odesc) {
    int idx = blockIdx.x * 256 + threadIdx.x;
    if (idx < NODESC) {
        int r = idx >> 7, c = idx & 127;
        int o = c - r;
        int sh = -1, s = 0;
        if (o >= 0 && o <= 15)                          { sh = 0; s = o; }
        else if (o >= 17 && o <= 31 && (o & 1) == 1)    { sh = 1; s = 16 + ((o - 17) >> 1); }
        else if (o >= 35 && o <= 63 && (o & 3) == 3)    { sh = 2; s = 24 + ((o - 35) >> 2); }
        else if (o >= 71 && o <= 127 && (o & 7) == 7)   { sh = 3; s = 32 + ((o - 71) >> 3); }
        unsigned short addr = (unsigned short)ZERO_SLOT;
        if (sh >= 0 && (r & ((1 << sh) - 1)) == 0) {
            int base = 0;
            for (int t = 0; t < s; ++t) {
                int oo, ss; seg_params(t, oo, ss);
                base += ((127 - oo) >> ss) + 1;
            }
            addr = (unsigned short)(VOFF + base + (r >> sh));
        }
        odesc[idx] = addr;
    } else if (idx < NODESC + NBUILD) {
        int i = idx - NODESC;
        unsigned int desc = 0;   // pad items read buf[0], write unused slot
        int base = 0;
        for (int t = 0; t < 40; ++t) {
            int oo, ss; seg_params(t, oo, ss);
            int cnt = ((127 - oo) >> ss) + 1;
            if (i < base + cnt) {
                int r = (i - base) << ss;
                int w = oo + 1;
                int k = 31 - __clz(w);
                int p2 = 1 << k;
                int lb = 129 * k - (p2 - 1);          // doubling-level base
                int s1 = lb + r;
                int s2 = lb + r + (w - p2);
                desc = (unsigned)s1 | ((unsigned)s2 << 16);
                break;
            }
            base += cnt;
        }
        bdesc[i] = desc;
    }
}

__global__ __launch_bounds__(256) void sp_main(const float* __restrict__ x,
                                               float* __restrict__ out,
                                               const unsigned int* __restrict__ bdesc,
                                               const unsigned short* __restrict__ odesc) {
    __shared__ float buf[LDS_WORDS];
    const int tid = threadIdx.x;
    const int slice = blockIdx.x;

    if (tid < NN) buf[tid] = x[(size_t)slice * NN + tid];
    if (tid == 255) buf[ZERO_SLOT] = 0.0f;
    __syncthreads();

    // Doubling table levels 1..7: P[k][i] = max(P[k-1][i], P[k-1][i+2^{k-1}])
    int base_prev = 0, base_cur = NN;
    #pragma unroll
    for (int k = 1; k <= 7; ++k) {
        int half = 1 << (k - 1);
        int len = (NN + 1) - (1 << k);
        if (tid < len)
            buf[base_cur + tid] = fmaxf(buf[base_prev + tid], buf[base_prev + tid + half]);
        __syncthreads();
        base_prev = base_cur;
        base_cur += len;
    }

    // Per-offset window-max value array (2548 entries + pad), descriptor-driven
    #pragma unroll
    for (int it = 0; it < NBUILD / 256; ++it) {
        int i = it * 256 + tid;
        unsigned int d = bdesc[i];
        buf[VOFF + i] = fmaxf(buf[d & 0xffff], buf[d >> 16]);
    }
    __syncthreads();

    // Output: 4096 float4 per slice, 16 per thread, coalesced; 1 ds_read per element
    float4* __restrict__ out_s = reinterpret_cast<float4*>(out + (size_t)slice * SLICE_ELEMS);
    const uint2* __restrict__ od = reinterpret_cast<const uint2*>(odesc);
    #pragma unroll
    for (int it = 0; it < 16; ++it) {
        int idx = it * 256 + tid;
        uint2 d = od[idx];
        float4 v;
        v.x = buf[d.x & 0xffff];
        v.y = buf[d.x >> 16];
        v.z = buf[d.y & 0xffff];
        v.w = buf[d.y >> 16];
        out_s[idx] = v;
    }
}

extern "C" void kernel_launch(void* const* d_in, const int* in_sizes, int n_in,
                              void* d_out, int out_size, void* d_ws, size_t ws_size,
                              hipStream_t stream) {
    const float* x = (const float*)d_in[0];
    float* out = (float*)d_out;
    unsigned int* bdesc = (unsigned int*)d_ws;                       // 2560 * 4 B
    unsigned short* odesc = (unsigned short*)((char*)d_ws + NBUILD * 4); // 16384 * 2 B, 8-B aligned

    const int init_items = NODESC + NBUILD;
    sp_init<<<dim3((init_items + 255) / 256), dim3(256), 0, stream>>>(bdesc, odesc);

    const int slices = in_sizes[0] / NN;   // 4096
    sp_main<<<dim3(slices), dim3(256), 0, stream>>>(x, out, bdesc, odesc);
}